// Round 3
// baseline (188.811 us; speedup 1.0000x reference)
//
#include <hip/hip_runtime.h>

#define T_DIM 2048
#define F_DIM 128
#define B_DIM 16
#define NS 10
#define NTILE 8        // tiles per row: 2048 / (64 lanes * 4 elems)
#define TPB 256        // 4 independent waves per block; wave = one (bf, si)

// Collision-free fast-math wrappers (avoid __exp2f/__log2f glibc macro clash).
__device__ __forceinline__ float fast_exp2(float x) { return __builtin_amdgcn_exp2f(x); }
__device__ __forceinline__ float fast_log2(float x) { return __builtin_amdgcn_logf(x); }

__global__ __launch_bounds__(TPB) void pcen_kernel(
    const float* __restrict__ x,
    const float* __restrict__ s_log,
    const float* __restrict__ alpha_log,
    const float* __restrict__ delta_log,
    const float* __restrict__ r_log,
    float* __restrict__ out)
{
    const int tid  = threadIdx.x;
    const int lane = tid & 63;
    const int gw   = blockIdx.x * (TPB / 64) + (tid >> 6);  // global wave id
    const int bf   = gw / NS;                               // row (b*F + f)
    const int si   = gw - bf * NS;                          // which s
    const int b    = bf >> 7;                               // bf / F_DIM
    const int f    = bf & (F_DIM - 1);

    const float4* xrow = (const float4*)(x + (size_t)bf * T_DIM);

    // Load all 8 tiles: lane l owns elems [k*256 + l*4, +4) -- perfectly
    // coalesced (64 lanes x 16B = 1KB contiguous per instruction).
    float4 xv[NTILE];
    #pragma unroll
    for (int k = 0; k < NTILE; ++k) xv[k] = xrow[k * 64 + lane];

    // Per-wave scalar parameters.
    const float s  = expf(s_log[si]);
    const float a  = 1.0f - s;
    const float alpha = expf(alpha_log[f]);
    const float delta = expf(delta_log[f]);
    const float r     = expf(r_log[f]);
    const float delta_r   = fast_exp2(r * fast_log2(delta));  // delta^r
    const float neg_alpha = -alpha;

    // Powers of a: pa[b] = a^(4 * 2^b), b = 0..5  (a^4 .. a^128).
    float pa[6];
    {
        float a2 = a * a;
        pa[0] = a2 * a2;
        #pragma unroll
        for (int bb = 1; bb < 6; ++bb) pa[bb] = pa[bb - 1] * pa[bb - 1];
    }
    const float a256 = pa[5] * pa[5];

    // a^(4*lane): product over set bits of lane (no shuffles needed).
    float a4l = 1.0f;
    #pragma unroll
    for (int bb = 0; bb < 6; ++bb) a4l *= ((lane >> bb) & 1) ? pa[bb] : 1.0f;

    // Phase 1: local inclusive scan of each lane's 4 elems (zero carry-in).
    float V[NTILE];
    #pragma unroll
    for (int k = 0; k < NTILE; ++k) {
        float c = s * xv[k].x;
        c = fmaf(a, c, s * xv[k].y);
        c = fmaf(a, c, s * xv[k].z);
        c = fmaf(a, c, s * xv[k].w);
        V[k] = c;
    }

    // Phase 2: Kogge-Stone linear scan across lanes. Multiplier per step is
    // the UNIFORM scalar a^(4d), so only v is scanned: one shuffle per step.
    // The 8 tile-scans are independent -> shuffle latency hidden by ILP.
    #pragma unroll
    for (int d = 1, bb = 0; d < 64; d <<= 1, ++bb) {
        #pragma unroll
        for (int k = 0; k < NTILE; ++k) {
            float up = __shfl_up(V[k], d);
            up = (lane >= d) ? up : 0.0f;
            V[k] = fmaf(pa[bb], up, V[k]);
        }
    }

    // Exclusive-per-lane and last-lane values (independent shuffles).
    float Ve[NTILE], Vl[NTILE];
    #pragma unroll
    for (int k = 0; k < NTILE; ++k) {
        float e = __shfl_up(V[k], 1);
        Ve[k] = (lane >= 1) ? e : 0.0f;
        Vl[k] = __shfl(V[k], 63);
    }

    // Tile-carry chain. Carry-in x0 reproduces y_0 = x_0 exactly as in the
    // reference ((1-s)*x0 + s*x0 = x0).
    float tc = __shfl(xv[0].x, 0);

    float* orow = out + (size_t)(((b * NS + si) * F_DIM) + f) * T_DIM;

    // Phase 3: recompute each lane's segment with its true carry-in and
    // fuse the PCEN pointwise math; perfectly coalesced float4 stores.
    #pragma unroll
    for (int k = 0; k < NTILE; ++k) {
        float cc = fmaf(a4l, tc, Ve[k]);   // smoother value just before segment
        const float4 xk = xv[k];
        float4 o;

        cc = fmaf(a, cc, s * xk.x);
        { float sm2 = fast_exp2(neg_alpha * fast_log2(cc + 1e-5f));
          float base = fmaf(xk.x, sm2, delta);
          o.x = fast_exp2(r * fast_log2(base)) - delta_r; }

        cc = fmaf(a, cc, s * xk.y);
        { float sm2 = fast_exp2(neg_alpha * fast_log2(cc + 1e-5f));
          float base = fmaf(xk.y, sm2, delta);
          o.y = fast_exp2(r * fast_log2(base)) - delta_r; }

        cc = fmaf(a, cc, s * xk.z);
        { float sm2 = fast_exp2(neg_alpha * fast_log2(cc + 1e-5f));
          float base = fmaf(xk.z, sm2, delta);
          o.z = fast_exp2(r * fast_log2(base)) - delta_r; }

        cc = fmaf(a, cc, s * xk.w);
        { float sm2 = fast_exp2(neg_alpha * fast_log2(cc + 1e-5f));
          float base = fmaf(xk.w, sm2, delta);
          o.w = fast_exp2(r * fast_log2(base)) - delta_r; }

        tc = fmaf(a256, tc, Vl[k]);        // carry into next tile

        ((float4*)orow)[k * 64 + lane] = o;
    }
}

extern "C" void kernel_launch(void* const* d_in, const int* in_sizes, int n_in,
                              void* d_out, int out_size, void* d_ws, size_t ws_size,
                              hipStream_t stream) {
    const float* x         = (const float*)d_in[0];
    const float* s_log     = (const float*)d_in[1];
    const float* alpha_log = (const float*)d_in[2];
    const float* delta_log = (const float*)d_in[3];
    const float* r_log     = (const float*)d_in[4];
    float* out = (float*)d_out;

    const int total_waves = B_DIM * F_DIM * NS;          // 20480
    const int blocks = total_waves / (TPB / 64);         // 5120

    pcen_kernel<<<dim3(blocks), dim3(TPB), 0, stream>>>(
        x, s_log, alpha_log, delta_log, r_log, out);
}